// Round 5
// baseline (122.945 us; speedup 1.0000x reference)
//
#include <hip/hip_runtime.h>
#include <hip/hip_bf16.h>

// LoRA conv experts, algebraically collapsed into ONE rank-64 separable pair:
//   W1[(e,r)][kx*256+c] = p_e * w_in[e,r,c,0,kx]    (64 x 768)
//   W2[o][ky*64+(e,r)]  = w_out[e,o,r,ky,0]         (256 x 192)
// Fused kernel: block = (b, y-stripe of 2); 4 halo h-rows in LDS, 2 out rows.
// R5: power-of-2 LDS strides (256 shorts = 0 mod 32 banks) + per-row XOR
// swizzle Q(r) = ((r^(r>>3))&7)<<3 (analytically conflict-free for both the
// b64 staging writes and b128 fragment reads); b64 staging (4x4 reg
// transpose); T14 prefetch of next row's x under the MFMA phase.

typedef __bf16 bf16x8 __attribute__((ext_vector_type(8)));
typedef __bf16 bf16x4 __attribute__((ext_vector_type(4)));
typedef float  f32x4  __attribute__((ext_vector_type(4)));

#define CIN_  256
#define COUT_ 256
#define M1    64
#define K1    768
#define K2    192
#define CS    256     // xs row stride (shorts): 128 dwords == 0 mod 32 banks
#define HS    256     // hs row stride (shorts)

static __device__ __forceinline__ unsigned short f2bf(float f) {
    union { float f; unsigned u; } v; v.f = f;
    unsigned r = v.u + 0x7FFFu + ((v.u >> 16) & 1u);
    return (unsigned short)(r >> 16);
}

static __device__ __forceinline__ int qsw(int r) {   // row -> column XOR (shorts)
    return ((r ^ (r >> 3)) & 7) << 3;
}

// ------------- prep: fold probs, reorder, cast to bf16 (W1, W2) -------------
__global__ void prep_weights(const float* __restrict__ probs,
                             const float* __restrict__ w_in,
                             const float* __restrict__ w_out,
                             unsigned short* __restrict__ W1,
                             unsigned short* __restrict__ W2) {
    int idx = blockIdx.x * blockDim.x + threadIdx.x;
    if (idx < M1 * K1) {
        int er = idx / K1, rem = idx % K1;
        int kx = rem / CIN_, c = rem % CIN_;
        int e = er >> 3;
        W1[idx] = f2bf(probs[e] * w_in[(er * CIN_ + c) * 3 + kx]);
    } else {
        int i2 = idx - M1 * K1;   // grid sized exactly (M1*K1 == COUT_*K2)
        int o = i2 / K2, rem = i2 % K2;
        int ky = rem / M1, er = rem % M1;
        int e = er >> 3, r = er & 7;
        W2[i2] = f2bf(w_out[((e * COUT_ + o) * 8 + r) * 3 + ky]);
    }
}

// ----------------------------- fused conv kernel -----------------------------
// grid = 16 b * 32 stripes = 512 blocks, 256 threads (4 waves), 65KB LDS.
__global__ __launch_bounds__(256, 2)
void fused_kernel(const float* __restrict__ x,
                  const unsigned short* __restrict__ W1,
                  const unsigned short* __restrict__ W2,
                  float* __restrict__ out) {
    __shared__ unsigned short xs[66 * CS];   // x tile transposed [ns][c^Q(ns-1)]
    __shared__ unsigned short hs[64 * HS];   // h tile [n][(yy*64+m)^Q(n)]
    const int bid  = blockIdx.x;
    const int b    = bid >> 5;
    const int y0   = (bid & 31) << 1;
    const int tid  = threadIdx.x;
    const int lane = tid & 63;
    const int wave = tid >> 6;       // wave = m-tile for h-phase, o-group for out
    const int g    = lane >> 4;
    const int lr   = lane & 15;

    // hoist W1 fragments for this wave's m-row (24 frags = 96 VGPR)
    bf16x8 w1f[3][8];
    {
        const unsigned short* w1p = W1 + (wave * 16 + lr) * K1 + g * 8;
        #pragma unroll
        for (int kx = 0; kx < 3; ++kx)
            #pragma unroll
            for (int cc = 0; cc < 8; ++cc)
                w1f[kx][cc] = *(const bf16x8*)(w1p + kx * CIN_ + cc * 32);
    }

    // zero xs halo rows ns=0 (n=-1) and ns=65 (n=64), once (full-row zero is
    // swizzle-safe: any column read of these rows returns 0)
    if (tid < 64) {
        int row = (tid < 32) ? 0 : 65;
        int col = (tid & 31) * 8;
        bf16x8 z = {};
        *(bf16x8*)&xs[row * CS + col] = z;
    }

    // staging map: thread covers c = it*64 + c0b .. +3 (4 consecutive),
    // n = n4 .. n4+3 -> 4x4 register transpose, 4 b64 writes per it.
    const int c0b = (tid >> 4) << 2;          // 0..60 step 4
    const int n4  = (tid & 15) << 2;

    f32x4 ld[4][4];   // [it][i] = x[it*64+c0b+i][n4..n4+3]

    // prefetch yy=0 (y = y0-1)
    {
        const int y = y0 - 1;
        if (y >= 0) {
            const float* xb = x + ((b * CIN_ + c0b) * 64 + y) * 64 + n4;
            #pragma unroll
            for (int it = 0; it < 4; ++it)
                #pragma unroll
                for (int i = 0; i < 4; ++i)
                    ld[it][i] = *(const f32x4*)(xb + (it * 64 + i) * 4096);
        } else {
            #pragma unroll
            for (int it = 0; it < 4; ++it)
                #pragma unroll
                for (int i = 0; i < 4; ++i)
                    ld[it][i] = (f32x4){0.f, 0.f, 0.f, 0.f};
        }
    }

    bf16x8 w2f[4][6];

    // ---------------- h-phase: 4 rows y = y0-1 .. y0+2 ----------------
    #pragma unroll
    for (int yy = 0; yy < 4; ++yy) {
        __syncthreads();                      // xs free
        // write prefetched row: 16 x ds_write_b64, swizzled
        #pragma unroll
        for (int it = 0; it < 4; ++it) {
            #pragma unroll
            for (int j = 0; j < 4; ++j) {
                int row = n4 + 1 + j;
                int col = (it * 64 + c0b) ^ qsw(n4 + j);
                bf16x4 pk;
                #pragma unroll
                for (int i = 0; i < 4; ++i) pk[i] = (__bf16)ld[it][i][j];
                *(bf16x4*)&xs[row * CS + col] = pk;
            }
        }
        __syncthreads();                      // xs ready

        // T14: issue next row's loads (fly under the MFMAs below);
        // at the last row, preload W2 fragments instead.
        if (yy < 3) {
            const int y = y0 + yy;            // = (y0-1) + (yy+1)
            if (y < 64) {
                const float* xb = x + ((b * CIN_ + c0b) * 64 + y) * 64 + n4;
                #pragma unroll
                for (int it = 0; it < 4; ++it)
                    #pragma unroll
                    for (int i = 0; i < 4; ++i)
                        ld[it][i] = *(const f32x4*)(xb + (it * 64 + i) * 4096);
            } else {
                #pragma unroll
                for (int it = 0; it < 4; ++it)
                    #pragma unroll
                    for (int i = 0; i < 4; ++i)
                        ld[it][i] = (f32x4){0.f, 0.f, 0.f, 0.f};
            }
        } else {
            #pragma unroll
            for (int ot = 0; ot < 4; ++ot)
                #pragma unroll
                for (int kc = 0; kc < 6; ++kc)
                    w2f[ot][kc] = *(const bf16x8*)(W2 +
                        ((wave * 4 + ot) * 16 + lr) * K2 + kc * 32 + g * 8);
        }

        f32x4 acc[4];
        #pragma unroll
        for (int i = 0; i < 4; ++i) acc[i] = (f32x4){0.f, 0.f, 0.f, 0.f};

        #pragma unroll
        for (int kx = 0; kx < 3; ++kx) {
            #pragma unroll
            for (int cc = 0; cc < 8; ++cc) {
                #pragma unroll
                for (int nt = 0; nt < 4; ++nt) {
                    int r = nt * 16 + lr + kx - 1;     // ns-1 (yy-invariant addr)
                    bf16x8 bfv = *(const bf16x8*)&xs[(r + 1) * CS +
                                                     ((cc * 32 + g * 8) ^ qsw(r))];
                    acc[nt] = __builtin_amdgcn_mfma_f32_16x16x32_bf16(
                        w1f[kx][cc], bfv, acc[nt], 0, 0, 0);
                }
            }
        }

        // D: col=lr (n), row=g*4+r2 (m). b64 into hs, swizzled by Q(n).
        #pragma unroll
        for (int nt = 0; nt < 4; ++nt) {
            int n = nt * 16 + lr;
            int col = (yy * 64 + wave * 16 + g * 4) ^ qsw(n);
            bf16x4 pk;
            #pragma unroll
            for (int r2 = 0; r2 < 4; ++r2) pk[r2] = (__bf16)acc[nt][r2];
            *(bf16x4*)&hs[n * HS + col] = pk;
        }
    }
    __syncthreads();                          // hs complete

    // ---------------- conv_out phase: 2 output rows ----------------
    #pragma unroll
    for (int ry = 0; ry < 2; ++ry) {
        f32x4 acc2[4][4];
        #pragma unroll
        for (int ot = 0; ot < 4; ++ot)
            #pragma unroll
            for (int nt = 0; nt < 4; ++nt) acc2[ot][nt] = (f32x4){0.f, 0.f, 0.f, 0.f};

        #pragma unroll
        for (int kc = 0; kc < 6; ++kc) {
            bf16x8 bfrag[4];
            #pragma unroll
            for (int nt = 0; nt < 4; ++nt) {
                int n = nt * 16 + lr;
                bfrag[nt] = *(const bf16x8*)&hs[n * HS +
                    ((ry * 64 + kc * 32 + g * 8) ^ qsw(n))];
            }
            #pragma unroll
            for (int ot = 0; ot < 4; ++ot)
                #pragma unroll
                for (int nt = 0; nt < 4; ++nt)
                    acc2[ot][nt] = __builtin_amdgcn_mfma_f32_16x16x32_bf16(
                        w2f[ot][kc], bfrag[nt], acc2[ot][nt], 0, 0, 0);
        }

        const int yo = y0 + ry;
        #pragma unroll
        for (int ot = 0; ot < 4; ++ot) {
            #pragma unroll
            for (int r2 = 0; r2 < 4; ++r2) {
                int o = (wave * 4 + ot) * 16 + g * 4 + r2;
                float* orow = out + ((b * COUT_ + o) * 64 + yo) * 64;
                #pragma unroll
                for (int nt = 0; nt < 4; ++nt)
                    orow[nt * 16 + lr] = acc2[ot][nt][r2];
            }
        }
    }
}

extern "C" void kernel_launch(void* const* d_in, const int* in_sizes, int n_in,
                              void* d_out, int out_size, void* d_ws, size_t ws_size,
                              hipStream_t stream) {
    const float* x     = (const float*)d_in[0];   // [16,256,64,64]
    const float* probs = (const float*)d_in[1];   // [8]
    const float* w_in  = (const float*)d_in[2];   // [8,8,256,1,3]
    const float* w_out = (const float*)d_in[3];   // [8,256,8,3,1]
    float* out = (float*)d_out;                   // [16,256,64,64] f32

    unsigned short* W1 = (unsigned short*)d_ws;   // 64*768 bf16
    unsigned short* W2 = W1 + M1 * K1;            // 256*192 bf16

    prep_weights<<<384, 256, 0, stream>>>(probs, w_in, w_out, W1, W2);
    fused_kernel<<<16 * 32, 256, 0, stream>>>(x, W1, W2, out);
}

// Round 6
// 62.034 us; speedup vs baseline: 1.9819x; 1.9819x over previous
//
#include <hip/hip_runtime.h>
#include <hip/hip_bf16.h>

// LoRA conv experts, algebraically collapsed into ONE rank-64 separable pair:
//   W1[(e,r)][kx*256+c] = p_e * w_in[e,r,c,0,kx]    (64 x 768)
//   W2[o][ky*64+(e,r)]  = w_out[e,o,r,ky,0]         (256 x 192)
// Fused kernel: block = (b, y-stripe of 2); 4 halo h-rows in LDS, 2 out rows.
// R6 = R4 schedule (low register pressure, no prefetch-under-MFMA) + R5's
// conflict-free LDS layout: stride 256 shorts (0 mod 32 banks) with per-row
// XOR swizzle Q(r) = ((r^(r>>3))&7)<<3, b64 staging writes streamed in
// 16-VGPR chunks. R5's spill lesson: never hold ld[4][4]+w1f+w2f live at once.

typedef __bf16 bf16x8 __attribute__((ext_vector_type(8)));
typedef __bf16 bf16x4 __attribute__((ext_vector_type(4)));
typedef float  f32x4  __attribute__((ext_vector_type(4)));

#define CIN_  256
#define COUT_ 256
#define M1    64
#define K1    768
#define K2    192
#define CS    256     // xs row stride (shorts): 128 dwords == 0 mod 32 banks
#define HS    256     // hs row stride (shorts)

static __device__ __forceinline__ unsigned short f2bf(float f) {
    union { float f; unsigned u; } v; v.f = f;
    unsigned r = v.u + 0x7FFFu + ((v.u >> 16) & 1u);
    return (unsigned short)(r >> 16);
}

static __device__ __forceinline__ int qsw(int r) {   // row -> column XOR (shorts)
    return ((r ^ (r >> 3)) & 7) << 3;
}

// ------------- prep: fold probs, reorder, cast to bf16 (W1, W2) -------------
__global__ void prep_weights(const float* __restrict__ probs,
                             const float* __restrict__ w_in,
                             const float* __restrict__ w_out,
                             unsigned short* __restrict__ W1,
                             unsigned short* __restrict__ W2) {
    int idx = blockIdx.x * blockDim.x + threadIdx.x;
    if (idx < M1 * K1) {
        int er = idx / K1, rem = idx % K1;
        int kx = rem / CIN_, c = rem % CIN_;
        int e = er >> 3;
        W1[idx] = f2bf(probs[e] * w_in[(er * CIN_ + c) * 3 + kx]);
    } else {
        int i2 = idx - M1 * K1;   // grid sized exactly (M1*K1 == COUT_*K2)
        int o = i2 / K2, rem = i2 % K2;
        int ky = rem / M1, er = rem % M1;
        int e = er >> 3, r = er & 7;
        W2[i2] = f2bf(w_out[((e * COUT_ + o) * 8 + r) * 3 + ky]);
    }
}

// ----------------------------- fused conv kernel -----------------------------
// grid = 16 b * 32 stripes = 512 blocks, 256 threads (4 waves), 65KB LDS.
__global__ __launch_bounds__(256, 2)
void fused_kernel(const float* __restrict__ x,
                  const unsigned short* __restrict__ W1,
                  const unsigned short* __restrict__ W2,
                  float* __restrict__ out) {
    __shared__ unsigned short xs[66 * CS];   // x tile transposed [ns][c^Q(ns-1)]
    __shared__ unsigned short hs[64 * HS];   // h tile [n][(yy*64+m)^Q(n)]
    const int bid  = blockIdx.x;
    const int b    = bid >> 5;
    const int y0   = (bid & 31) << 1;
    const int tid  = threadIdx.x;
    const int lane = tid & 63;
    const int wave = tid >> 6;       // wave = m-tile for h-phase, o-group for out
    const int g    = lane >> 4;
    const int lr   = lane & 15;

    // hoist W1 fragments for this wave's m-row (24 frags = 96 VGPR)
    bf16x8 w1f[3][8];
    {
        const unsigned short* w1p = W1 + (wave * 16 + lr) * K1 + g * 8;
        #pragma unroll
        for (int kx = 0; kx < 3; ++kx)
            #pragma unroll
            for (int cc = 0; cc < 8; ++cc)
                w1f[kx][cc] = *(const bf16x8*)(w1p + kx * CIN_ + cc * 32);
    }

    // zero xs halo rows ns=0 (n=-1) and ns=65 (n=64), once (whole-row zero is
    // swizzle-safe; staging only writes rows 1..64)
    if (tid < 64) {
        int row = (tid < 32) ? 0 : 65;
        int col = (tid & 31) * 8;
        bf16x8 z = {};
        *(bf16x8*)&xs[row * CS + col] = z;
    }

    // staging map: thread covers c = it*64 + c0b .. +3, n = n4 .. n4+3;
    // per it: load 4 float4 (16 VGPR), 4x4 transpose, 4 x ds_write_b64.
    const int c0b = (tid >> 4) << 2;          // 0..60 step 4
    const int n4  = (tid & 15) << 2;

    // ---------------- h-phase: 4 rows y = y0-1 .. y0+2 ----------------
    for (int yy = 0; yy < 4; ++yy) {
        const int y = y0 - 1 + yy;
        const bool yok = ((unsigned)y < 64u);
        __syncthreads();                      // xs free
        const float* xb = x + ((b * CIN_ + c0b) * 64 + (yok ? y : 0)) * 64 + n4;
        #pragma unroll
        for (int it = 0; it < 4; ++it) {
            f32x4 ld[4];
            if (yok) {
                #pragma unroll
                for (int i = 0; i < 4; ++i)
                    ld[i] = *(const f32x4*)(xb + (it * 64 + i) * 4096);
            } else {
                #pragma unroll
                for (int i = 0; i < 4; ++i) ld[i] = (f32x4){0.f, 0.f, 0.f, 0.f};
            }
            #pragma unroll
            for (int j = 0; j < 4; ++j) {
                int row = n4 + 1 + j;
                int col = (it * 64 + c0b) ^ qsw(n4 + j);
                bf16x4 pk;
                #pragma unroll
                for (int i = 0; i < 4; ++i) pk[i] = (__bf16)ld[i][j];
                *(bf16x4*)&xs[row * CS + col] = pk;
            }
        }
        __syncthreads();                      // xs ready

        f32x4 acc[4];
        #pragma unroll
        for (int i = 0; i < 4; ++i) acc[i] = (f32x4){0.f, 0.f, 0.f, 0.f};

        #pragma unroll
        for (int kx = 0; kx < 3; ++kx) {
            #pragma unroll
            for (int cc = 0; cc < 8; ++cc) {
                int co = cc * 32 + g * 8;
                #pragma unroll
                for (int nt = 0; nt < 4; ++nt) {
                    int r = nt * 16 + lr + kx - 1;     // logical n of this frag
                    bf16x8 bfv = *(const bf16x8*)&xs[(r + 1) * CS + (co ^ qsw(r))];
                    acc[nt] = __builtin_amdgcn_mfma_f32_16x16x32_bf16(
                        w1f[kx][cc], bfv, acc[nt], 0, 0, 0);
                }
            }
        }

        // D: col=lr (n), row=g*4+r2 (m). b64 into hs, swizzled by Q(n).
        #pragma unroll
        for (int nt = 0; nt < 4; ++nt) {
            int n = nt * 16 + lr;
            int col = (yy * 64 + wave * 16 + g * 4) ^ qsw(n);
            bf16x4 pk;
            #pragma unroll
            for (int r2 = 0; r2 < 4; ++r2) pk[r2] = (__bf16)acc[nt][r2];
            *(bf16x4*)&hs[n * HS + col] = pk;
        }
    }
    __syncthreads();                          // hs complete (w1f dead here)

    // ---------------- conv_out phase: 2 output rows ----------------
    bf16x8 w2f[4][6];                         // reuses w1f's registers
    #pragma unroll
    for (int ot = 0; ot < 4; ++ot)
        #pragma unroll
        for (int kc = 0; kc < 6; ++kc)
            w2f[ot][kc] = *(const bf16x8*)(W2 + ((wave * 4 + ot) * 16 + lr) * K2 +
                                           kc * 32 + g * 8);

    #pragma unroll
    for (int ry = 0; ry < 2; ++ry) {
        f32x4 acc2[4][4];
        #pragma unroll
        for (int ot = 0; ot < 4; ++ot)
            #pragma unroll
            for (int nt = 0; nt < 4; ++nt) acc2[ot][nt] = (f32x4){0.f, 0.f, 0.f, 0.f};

        #pragma unroll
        for (int kc = 0; kc < 6; ++kc) {
            bf16x8 bfrag[4];
            #pragma unroll
            for (int nt = 0; nt < 4; ++nt) {
                int n = nt * 16 + lr;
                bfrag[nt] = *(const bf16x8*)&hs[n * HS +
                    ((ry * 64 + kc * 32 + g * 8) ^ qsw(n))];
            }
            #pragma unroll
            for (int ot = 0; ot < 4; ++ot)
                #pragma unroll
                for (int nt = 0; nt < 4; ++nt)
                    acc2[ot][nt] = __builtin_amdgcn_mfma_f32_16x16x32_bf16(
                        w2f[ot][kc], bfrag[nt], acc2[ot][nt], 0, 0, 0);
        }

        const int yo = y0 + ry;
        #pragma unroll
        for (int ot = 0; ot < 4; ++ot) {
            #pragma unroll
            for (int r2 = 0; r2 < 4; ++r2) {
                int o = (wave * 4 + ot) * 16 + g * 4 + r2;
                float* orow = out + ((b * COUT_ + o) * 64 + yo) * 64;
                #pragma unroll
                for (int nt = 0; nt < 4; ++nt)
                    orow[nt * 16 + lr] = acc2[ot][nt][r2];
            }
        }
    }
}

extern "C" void kernel_launch(void* const* d_in, const int* in_sizes, int n_in,
                              void* d_out, int out_size, void* d_ws, size_t ws_size,
                              hipStream_t stream) {
    const float* x     = (const float*)d_in[0];   // [16,256,64,64]
    const float* probs = (const float*)d_in[1];   // [8]
    const float* w_in  = (const float*)d_in[2];   // [8,8,256,1,3]
    const float* w_out = (const float*)d_in[3];   // [8,256,8,3,1]
    float* out = (float*)d_out;                   // [16,256,64,64] f32

    unsigned short* W1 = (unsigned short*)d_ws;   // 64*768 bf16
    unsigned short* W2 = W1 + M1 * K1;            // 256*192 bf16

    prep_weights<<<384, 256, 0, stream>>>(probs, w_in, w_out, W1, W2);
    fused_kernel<<<16 * 32, 256, 0, stream>>>(x, W1, W2, out);
}